// Round 6
// baseline (424.116 us; speedup 1.0000x reference)
//
#include <hip/hip_runtime.h>
#include <hip/hip_bf16.h>
#include <stdint.h>
#include <stddef.h>

#define N_ 50000
#define E_ 600000
#define F_ 128
#define H_ 128
#define G_ 64
#define P_ 32
#define C_ 10
#define NB_ 49   // scan blocks: ceil(N/1024)

typedef __hip_bfloat16 bf16;
typedef __attribute__((ext_vector_type(8))) short short8;
typedef __attribute__((ext_vector_type(4))) float float4v;

__device__ __forceinline__ unsigned short f2us(float x){ bf16 h = __float2bfloat16(x); return *(unsigned short*)&h; }
__device__ __forceinline__ float blo(unsigned int u){ return __uint_as_float(u<<16); }
__device__ __forceinline__ float bhi(unsigned int u){ return __uint_as_float(u & 0xFFFF0000u); }
__device__ __forceinline__ unsigned int packbf(float lo, float hi){ return ((unsigned int)f2us(hi)<<16) | f2us(lo); }
__device__ __forceinline__ float eluf(float x){ return x>0.f ? x : __expf(x)-1.f; }
__device__ __forceinline__ float bnf(float x,float m,float v,float g,float b){ return (x-m)*rsqrtf(v+1e-5f)*g+b; }
__device__ __forceinline__ float lrelu(float x){ return x>0.f ? x : 0.2f*x; }
__device__ __forceinline__ float expc(float x){ return __expf(fminf(x, 50.f)); }
__device__ __forceinline__ void atomAddF(float* a, float v){ unsafeAtomicAdd(a, v); }
__device__ __forceinline__ float xred4(float v){  // sum across the 4 edge-groups (bits 4,5 of lane)
  v += __shfl_xor(v, 16, 64);
  v += __shfl_xor(v, 32, 64);
  return v;
}

// ---------------- weight prep: per-lane MFMA B-fragment layout ----------------
// WF[m][tile][kc][lane][j] = W_m[k][n],  k = kc*32 + (lane>>4)*8 + j,  n = tile*16 + (lane&15)
__global__ __launch_bounds__(256) void k_wprep(const float* __restrict__ W1, const float* __restrict__ Wl,
    const float* __restrict__ Wr, const float* __restrict__ Wg, unsigned short* __restrict__ WT){
  int idx = blockIdx.x*256 + threadIdx.x;
  if(idx >= 6*16384) return;
  int m    = idx >> 14;
  int tile = (idx >> 11) & 7;
  int kc   = (idx >> 9) & 3;
  int lane = (idx >> 3) & 63;
  int j    = idx & 7;
  int k = kc*32 + (lane>>4)*8 + j;
  int n = tile*16 + (lane&15);
  float v;
  if(m==0)      v = W1[k*128+n];
  else if(m==1) v = Wl[k*128+n];
  else if(m==2) v = Wr[k*128+n];
  else          v = Wg[k*384 + (m-3)*128 + n];
  WT[idx] = f2us(v);
}

// vs3/vd3 for fused GAT logits + bn1 scale/shift (bias folded)
__global__ __launch_bounds__(384) void k_vprep(const float* __restrict__ Wg, const float* __restrict__ a_src,
    const float* __restrict__ a_dst,
    const float* __restrict__ b1, const float* __restrict__ g1, const float* __restrict__ be1,
    const float* __restrict__ m1, const float* __restrict__ v1,
    float* __restrict__ vs3, float* __restrict__ vd3,
    float* __restrict__ sc1, float* __restrict__ sh1){
  int t = threadIdx.x;
  if(t >= 384) return;
  if(t < 128){
    float s = g1[t] * rsqrtf(v1[t] + 1e-5f);
    sc1[t] = s;
    sh1[t] = (b1[t] - m1[t]) * s + be1[t];
  }
  int h = t >> 7, f = t & 127;
  const float4* wr = (const float4*)(Wg + (size_t)f*384 + h*128);
  const float4* as = (const float4*)(a_src + h*128);
  const float4* ad = (const float4*)(a_dst + h*128);
  float s = 0.f, d = 0.f;
  #pragma unroll 8
  for(int j=0;j<32;j++){
    float4 wv = wr[j], av = as[j], dv = ad[j];
    s += wv.x*av.x + wv.y*av.y + wv.z*av.z + wv.w*av.w;
    d += wv.x*dv.x + wv.y*dv.y + wv.z*dv.z + wv.w*dv.w;
  }
  vs3[t] = s; vd3[t] = d;
}

// ---------------- MFMA GEMM helpers (LDS-free, sync-free) ----------------
__device__ __forceinline__ void load_Afrag_bf16(const bf16* A, int row, int lane, short8 af[4]){
  const unsigned short* ap = (const unsigned short*)A + (size_t)row*128 + (lane>>4)*8;
  #pragma unroll
  for(int kc=0;kc<4;kc++) af[kc] = *(const short8*)(ap + kc*32);
}
__device__ __forceinline__ void mfma_pass_g(const unsigned short* __restrict__ WB, const short8 af[4],
                                            int lane, float4v acc[8]){
  #pragma unroll
  for(int tile=0;tile<8;tile++){
    #pragma unroll
    for(int kc=0;kc<4;kc++){
      short8 bfv = *(const short8*)(WB + (((tile*4+kc)*64 + lane)<<3));
      acc[tile] = __builtin_amdgcn_mfma_f32_16x16x32_bf16(af[kc], bfv, acc[tile], 0, 0, 0);
    }
  }
}

// h(bf16) = X(f32) @ W1
__global__ __launch_bounds__(256) void k_mm_x(const float* __restrict__ X, const unsigned short* __restrict__ WTg,
                                              bf16* __restrict__ HB){
  const int tid = threadIdx.x, lane = tid&63, w = tid>>6;
  const int row0 = blockIdx.x*64;
  int arow = row0 + w*16 + (lane&15);
  int ar = arow < N_ ? arow : N_-1;
  const float* ap = X + (size_t)ar*128 + (lane>>4)*8;
  short8 af[4];
  #pragma unroll
  for(int kc=0;kc<4;kc++){
    float4 a = *(const float4*)(ap + kc*32);
    float4 b = *(const float4*)(ap + kc*32 + 4);
    short8 v;
    v[0]=(short)f2us(a.x); v[1]=(short)f2us(a.y); v[2]=(short)f2us(a.z); v[3]=(short)f2us(a.w);
    v[4]=(short)f2us(b.x); v[5]=(short)f2us(b.y); v[6]=(short)f2us(b.z); v[7]=(short)f2us(b.w);
    af[kc]=v;
  }
  float4v acc[8];
  #pragma unroll
  for(int t=0;t<8;t++){ acc[t][0]=0.f; acc[t][1]=0.f; acc[t][2]=0.f; acc[t][3]=0.f; }
  mfma_pass_g(WTg, af, lane, acc);
  const int colb = lane&15, q = lane>>4;
  unsigned short* ob = (unsigned short*)HB;
  #pragma unroll
  for(int r=0;r<4;r++){
    int ro = row0 + w*16 + q*4 + r;
    if(ro < N_){
      #pragma unroll
      for(int tile=0;tile<8;tile++)
        ob[(size_t)ro*128 + tile*16 + colb] = f2us(acc[tile][r]);
    }
  }
}

// h2(bf16) = elu(bn2( mean@Wl + h1@Wr + bs )) ; fused GAT logits als4/ald4 = h2 . vs/vd
__global__ __launch_bounds__(256) void k_sage_mm_att(const bf16* __restrict__ MaB, const bf16* __restrict__ H1B,
    const unsigned short* __restrict__ WlF, const unsigned short* __restrict__ WrF,
    const float* __restrict__ bs, const float* __restrict__ g2, const float* __restrict__ be2,
    const float* __restrict__ m2, const float* __restrict__ v2,
    const float* __restrict__ vs3, const float* __restrict__ vd3,
    bf16* __restrict__ H2B, float* __restrict__ als4, float* __restrict__ ald4){
  const int tid = threadIdx.x, lane = tid&63, w = tid>>6;
  const int row0 = blockIdx.x*64;
  int arow = row0 + w*16 + (lane&15);
  int ar = arow < N_ ? arow : N_-1;
  float4v acc[8];
  #pragma unroll
  for(int t=0;t<8;t++){ acc[t][0]=0.f; acc[t][1]=0.f; acc[t][2]=0.f; acc[t][3]=0.f; }
  short8 af[4];
  load_Afrag_bf16(MaB, ar, lane, af);
  mfma_pass_g(WlF, af, lane, acc);
  load_Afrag_bf16(H1B, ar, lane, af);
  mfma_pass_g(WrF, af, lane, acc);

  const int colb = lane&15, q = lane>>4;
  float vsv[24], vdv[24];
  #pragma unroll
  for(int h=0;h<3;h++){
    #pragma unroll
    for(int tile=0;tile<8;tile++){
      vsv[h*8+tile] = vs3[h*128 + tile*16 + colb];
      vdv[h*8+tile] = vd3[h*128 + tile*16 + colb];
    }
  }
  unsigned short* ob = (unsigned short*)H2B;
  #pragma unroll
  for(int tile=0;tile<8;tile++){
    int col = tile*16 + colb;
    float bsv=bs[col], gv=g2[col], bev=be2[col], mv=m2[col], vv=v2[col];
    #pragma unroll
    for(int r=0;r<4;r++){
      int ro = row0 + w*16 + q*4 + r;
      float x = eluf(bnf(acc[tile][r] + bsv, mv, vv, gv, bev));
      acc[tile][r] = x;
      if(ro < N_) ob[(size_t)ro*128 + col] = f2us(x);
    }
  }
  #pragma unroll
  for(int r=0;r<4;r++){
    int ro = row0 + w*16 + q*4 + r;
    #pragma unroll
    for(int h=0;h<3;h++){
      float ps=0.f, pd=0.f;
      #pragma unroll
      for(int tile=0;tile<8;tile++){ ps += acc[tile][r]*vsv[h*8+tile]; pd += acc[tile][r]*vdv[h*8+tile]; }
      #pragma unroll
      for(int o=8;o>0;o>>=1){ ps += __shfl_down(ps,o,16); pd += __shfl_down(pd,o,16); }
      if(colb==0 && ro<N_){ als4[ro*4+h] = ps; ald4[ro*4+h] = pd; }
    }
  }
}

// h3(bf16) = elu(bn3( sum_h U_h @ Wg_h + bg ))  where U = [U0|U1|U2] is N x 384
__global__ __launch_bounds__(256) void k_gat_mm3(const bf16* __restrict__ U, const unsigned short* __restrict__ WgF,
    const float* __restrict__ bg, const float* __restrict__ g3, const float* __restrict__ be3,
    const float* __restrict__ m3, const float* __restrict__ v3, bf16* __restrict__ H3B){
  const int tid = threadIdx.x, lane = tid&63, w = tid>>6;
  const int row0 = blockIdx.x*64;
  int arow = row0 + w*16 + (lane&15);
  int ar = arow < N_ ? arow : N_-1;
  float4v acc[8];
  #pragma unroll
  for(int t=0;t<8;t++){ acc[t][0]=0.f; acc[t][1]=0.f; acc[t][2]=0.f; acc[t][3]=0.f; }
  short8 af[4];
  for(int hh=0; hh<3; hh++){
    const unsigned short* ap = (const unsigned short*)U + (size_t)ar*384 + hh*128 + (lane>>4)*8;
    #pragma unroll
    for(int kc=0;kc<4;kc++) af[kc] = *(const short8*)(ap + kc*32);
    mfma_pass_g(WgF + hh*16384, af, lane, acc);
  }
  const int colb = lane&15, q = lane>>4;
  unsigned short* ob = (unsigned short*)H3B;
  #pragma unroll
  for(int tile=0;tile<8;tile++){
    int col = tile*16 + colb;
    float bgv=bg[col], gv=g3[col], bev=be3[col], mv=m3[col], vv=v3[col];
    #pragma unroll
    for(int r=0;r<4;r++){
      int ro = row0 + w*16 + q*4 + r;
      if(ro < N_){
        float x = acc[tile][r] + bgv;
        ob[(size_t)ro*128 + col] = f2us(eluf(bnf(x, mv, vv, gv, bev)));
      }
    }
  }
}

// ---------------- CSR build ----------------
__global__ __launch_bounds__(256) void k_count(const int* __restrict__ dst, int* __restrict__ cnt){
  int e = blockIdx.x*256 + threadIdx.x;
  if(e < E_) atomicAdd(&cnt[dst[e]], 1);
}

__global__ __launch_bounds__(1024) void k_scan1(const int* __restrict__ cnt, int* __restrict__ row_ptr,
                                                float* __restrict__ dinv, int* __restrict__ bsum){
  __shared__ int wsum[16];
  const int t = threadIdx.x, lane = t & 63, wid = t >> 6;
  int i = blockIdx.x*1024 + t;
  int v = (i<N_) ? cnt[i] : 0;
  int x = v;
  #pragma unroll
  for(int o=1;o<64;o<<=1){
    int y = __shfl_up(x, o, 64);
    if(lane >= o) x += y;
  }
  if(lane==63) wsum[wid] = x;
  __syncthreads();
  if(wid==0){
    int s = (lane<16) ? wsum[lane] : 0;
    #pragma unroll
    for(int o=1;o<16;o<<=1){
      int y = __shfl_up(s, o, 64);
      if(lane >= o) s += y;
    }
    if(lane<16) wsum[lane] = s;
  }
  __syncthreads();
  int waveoff = (wid>0) ? wsum[wid-1] : 0;
  int incl = waveoff + x;
  if(i<N_){
    row_ptr[i] = incl - v;
    dinv[i] = rsqrtf((float)v + 1.f);
  }
  if(t==1023) bsum[blockIdx.x] = incl;
}

__global__ __launch_bounds__(64) void k_scan2(const int* __restrict__ bsum, int* __restrict__ boff,
                                              int* __restrict__ row_ptr){
  int lane = threadIdx.x;
  int v = (lane < NB_) ? bsum[lane] : 0;
  int x = v;
  #pragma unroll
  for(int o=1;o<64;o<<=1){
    int y = __shfl_up(x, o, 64);
    if(lane >= o) x += y;
  }
  if(lane < NB_) boff[lane] = x - v;
  if(lane == 63) row_ptr[N_] = x;
}

__global__ __launch_bounds__(256) void k_scan3(int* __restrict__ row_ptr, const int* __restrict__ boff,
                                               int* __restrict__ tmp){
  int i = blockIdx.x*256 + threadIdx.x;
  if(i < N_){
    int r = row_ptr[i] + boff[i>>10];
    row_ptr[i] = r;
    tmp[i] = r;
  }
}

__global__ __launch_bounds__(256) void k_scatter(const int* __restrict__ src, const int* __restrict__ dst,
                                                 int* __restrict__ tmp, int* __restrict__ esrc){
  int e = blockIdx.x*256 + threadIdx.x;
  if(e < E_){
    int d = dst[e];
    int pos = atomicAdd(&tmp[d], 1);
    esrc[pos] = src[e];
  }
}

// ---------------- CSR gather kernels: 4 rows per wave-load ----------------
// lane = (g<<4)|c : g = edge slot (0..3), c = 16 lanes x uint4 = one 256B row.
// Butterfly xor(16/32) touches only the g bits -> every lane ends with the cross-group sum.

__global__ __launch_bounds__(256) void k_gcn_gather(const int* __restrict__ row_ptr, const int* __restrict__ esrc,
    const float* __restrict__ dinv, const bf16* __restrict__ HB,
    const float* __restrict__ sc1, const float* __restrict__ sh1, bf16* __restrict__ H1B){
  int n = blockIdx.x*4 + (threadIdx.x>>6);
  int lane = threadIdx.x & 63;
  if(n >= N_) return;
  const int g = lane>>4, c = lane&15;
  int beg = row_ptr[n], end = row_ptr[n+1];
  float dn = dinv[n];
  const unsigned short* hb = (const unsigned short*)HB;
  // self term (group 0 only)
  uint4 ps = *(const uint4*)(hb + (size_t)n*H_ + c*8);
  float cw = (g==0) ? dn*dn : 0.f;
  float a[8];
  a[0]=cw*blo(ps.x); a[1]=cw*bhi(ps.x); a[2]=cw*blo(ps.y); a[3]=cw*bhi(ps.y);
  a[4]=cw*blo(ps.z); a[5]=cw*bhi(ps.z); a[6]=cw*blo(ps.w); a[7]=cw*bhi(ps.w);
  for(int e=beg; e<end; e+=4){
    int t = end - e;
    bool act = g < t;
    int s = esrc[e + (act ? g : 0)];
    float w = act ? dinv[s]*dn : 0.f;
    uint4 p = *(const uint4*)(hb + (size_t)s*H_ + c*8);
    a[0]+=w*blo(p.x); a[1]+=w*bhi(p.x); a[2]+=w*blo(p.y); a[3]+=w*bhi(p.y);
    a[4]+=w*blo(p.z); a[5]+=w*bhi(p.z); a[6]+=w*blo(p.w); a[7]+=w*bhi(p.w);
  }
  #pragma unroll
  for(int k=0;k<8;k++) a[k] = xred4(a[k]);
  if(g==0){
    float4 s0 = *(const float4*)(sc1 + c*8);
    float4 s1 = *(const float4*)(sc1 + c*8 + 4);
    float4 t0 = *(const float4*)(sh1 + c*8);
    float4 t1 = *(const float4*)(sh1 + c*8 + 4);
    uint4 o;
    o.x = packbf(eluf(a[0]*s0.x+t0.x), eluf(a[1]*s0.y+t0.y));
    o.y = packbf(eluf(a[2]*s0.z+t0.z), eluf(a[3]*s0.w+t0.w));
    o.z = packbf(eluf(a[4]*s1.x+t1.x), eluf(a[5]*s1.y+t1.y));
    o.w = packbf(eluf(a[6]*s1.z+t1.z), eluf(a[7]*s1.w+t1.w));
    *(uint4*)((unsigned short*)H1B + (size_t)n*H_ + c*8) = o;
  }
}

__global__ __launch_bounds__(256) void k_sage_gather(const int* __restrict__ row_ptr, const int* __restrict__ esrc,
    const bf16* __restrict__ H1B, bf16* __restrict__ MeanB){
  int n = blockIdx.x*4 + (threadIdx.x>>6);
  int lane = threadIdx.x & 63;
  if(n >= N_) return;
  const int g = lane>>4, c = lane&15;
  int beg = row_ptr[n], end = row_ptr[n+1];
  const unsigned short* hb = (const unsigned short*)H1B;
  float a[8];
  #pragma unroll
  for(int k=0;k<8;k++) a[k]=0.f;
  for(int e=beg; e<end; e+=4){
    int t = end - e;
    bool act = g < t;
    int s = esrc[e + (act ? g : 0)];
    float w = act ? 1.f : 0.f;
    uint4 p = *(const uint4*)(hb + (size_t)s*H_ + c*8);
    a[0]+=w*blo(p.x); a[1]+=w*bhi(p.x); a[2]+=w*blo(p.y); a[3]+=w*bhi(p.y);
    a[4]+=w*blo(p.z); a[5]+=w*bhi(p.z); a[6]+=w*blo(p.w); a[7]+=w*bhi(p.w);
  }
  #pragma unroll
  for(int k=0;k<8;k++) a[k] = xred4(a[k]);
  if(g==0){
    float inv = 1.f / fmaxf((float)(end-beg), 1.f);
    uint4 o;
    o.x = packbf(a[0]*inv, a[1]*inv);
    o.y = packbf(a[2]*inv, a[3]*inv);
    o.z = packbf(a[4]*inv, a[5]*inv);
    o.w = packbf(a[6]*inv, a[7]*inv);
    *(uint4*)((unsigned short*)MeanB + (size_t)n*H_ + c*8) = o;
  }
}

#define GAT_STORE8(A, I, OFFH)                                              \
  {                                                                         \
    uint4 o;                                                                \
    o.x = packbf(A[0]*(I), A[1]*(I));                                       \
    o.y = packbf(A[2]*(I), A[3]*(I));                                       \
    o.z = packbf(A[4]*(I), A[5]*(I));                                       \
    o.w = packbf(A[6]*(I), A[7]*(I));                                       \
    *(uint4*)(ub + (size_t)n*384 + (OFFH)*128 + c*8) = o;                   \
  }

// GAT aggregation in h2-space, fused edge weights, 4 rows/wave-load.
__global__ __launch_bounds__(256) void k_gat_agg(const int* __restrict__ row_ptr, const int* __restrict__ esrc,
    const float* __restrict__ als4, const float* __restrict__ ald4,
    const bf16* __restrict__ H2B, bf16* __restrict__ U){
  int n = blockIdx.x*4 + (threadIdx.x>>6);
  int lane = threadIdx.x & 63;
  if(n >= N_) return;
  const int g = lane>>4, c = lane&15;
  int beg = row_ptr[n], end = row_ptr[n+1];
  float4 adn = *(const float4*)(ald4 + (size_t)n*4);
  float4 asn = *(const float4*)(als4 + (size_t)n*4);
  float es0 = expc(lrelu(asn.x + adn.x));
  float es1 = expc(lrelu(asn.y + adn.y));
  float es2 = expc(lrelu(asn.z + adn.z));
  const unsigned short* hb = (const unsigned short*)H2B;
  // self term (group 0 only)
  uint4 ps = *(const uint4*)(hb + (size_t)n*H_ + c*8);
  float w0 = (g==0) ? es0 : 0.f;
  float w1 = (g==0) ? es1 : 0.f;
  float w2 = (g==0) ? es2 : 0.f;
  float f0=blo(ps.x), f1=bhi(ps.x), f2=blo(ps.y), f3=bhi(ps.y);
  float f4=blo(ps.z), f5=bhi(ps.z), f6=blo(ps.w), f7=bhi(ps.w);
  float a0[8], a1[8], a2[8];
  a0[0]=w0*f0; a0[1]=w0*f1; a0[2]=w0*f2; a0[3]=w0*f3; a0[4]=w0*f4; a0[5]=w0*f5; a0[6]=w0*f6; a0[7]=w0*f7;
  a1[0]=w1*f0; a1[1]=w1*f1; a1[2]=w1*f2; a1[3]=w1*f3; a1[4]=w1*f4; a1[5]=w1*f5; a1[6]=w1*f6; a1[7]=w1*f7;
  a2[0]=w2*f0; a2[1]=w2*f1; a2[2]=w2*f2; a2[3]=w2*f3; a2[4]=w2*f4; a2[5]=w2*f5; a2[6]=w2*f6; a2[7]=w2*f7;
  float den0 = w0, den1 = w1, den2 = w2;
  for(int e=beg; e<end; e+=4){
    int t = end - e;
    bool act = g < t;
    int s = esrc[e + (act ? g : 0)];
    float4 asl = *(const float4*)(als4 + (size_t)s*4);
    float u0 = act ? expc(lrelu(asl.x + adn.x)) : 0.f;
    float u1 = act ? expc(lrelu(asl.y + adn.y)) : 0.f;
    float u2 = act ? expc(lrelu(asl.z + adn.z)) : 0.f;
    uint4 p = *(const uint4*)(hb + (size_t)s*H_ + c*8);
    den0 += u0; den1 += u1; den2 += u2;
    float q0=blo(p.x), q1=bhi(p.x), q2=blo(p.y), q3=bhi(p.y);
    float q4=blo(p.z), q5=bhi(p.z), q6=blo(p.w), q7=bhi(p.w);
    a0[0]+=u0*q0; a0[1]+=u0*q1; a0[2]+=u0*q2; a0[3]+=u0*q3;
    a0[4]+=u0*q4; a0[5]+=u0*q5; a0[6]+=u0*q6; a0[7]+=u0*q7;
    a1[0]+=u1*q0; a1[1]+=u1*q1; a1[2]+=u1*q2; a1[3]+=u1*q3;
    a1[4]+=u1*q4; a1[5]+=u1*q5; a1[6]+=u1*q6; a1[7]+=u1*q7;
    a2[0]+=u2*q0; a2[1]+=u2*q1; a2[2]+=u2*q2; a2[3]+=u2*q3;
    a2[4]+=u2*q4; a2[5]+=u2*q5; a2[6]+=u2*q6; a2[7]+=u2*q7;
  }
  #pragma unroll
  for(int k=0;k<8;k++){ a0[k]=xred4(a0[k]); a1[k]=xred4(a1[k]); a2[k]=xred4(a2[k]); }
  den0 = xred4(den0); den1 = xred4(den1); den2 = xred4(den2);
  float i0 = 1.f/(3.f*den0), i1 = 1.f/(3.f*den1), i2 = 1.f/(3.f*den2);
  unsigned short* ub = (unsigned short*)U;
  if(g==0)      GAT_STORE8(a0, i0, 0)
  else if(g==1) GAT_STORE8(a1, i1, 1)
  else if(g==2) GAT_STORE8(a2, i2, 2)
}

// pure pool over graphs (h3 already activated); also counts graph sizes per segment
#define NPW_ 16
__global__ __launch_bounds__(256) void k_h3pool(const bf16* __restrict__ H3B,
    const int* __restrict__ batch, float* __restrict__ pooled, float* __restrict__ gcnt){
  int wave = blockIdx.x*4 + (threadIdx.x>>6);
  int lane = threadIdx.x & 63;
  int n0 = wave*NPW_;
  if(n0 >= N_) return;
  int n1 = n0 + NPW_; if(n1 > N_) n1 = N_;
  int f0 = lane*2, f1 = f0+1;
  float r0=0.f, r1=0.f;
  int cur = batch[n0];
  int seg = 0;
  for(int n=n0; n<n1; n++){
    int b = batch[n];
    if(b != cur){
      atomAddF(&pooled[cur*H_ + f0], r0);
      atomAddF(&pooled[cur*H_ + f1], r1);
      if(lane==0) atomAddF(&gcnt[cur], (float)seg);
      r0 = 0.f; r1 = 0.f; seg = 0; cur = b;
    }
    unsigned int hv = *(const unsigned int*)((const unsigned short*)H3B + (size_t)n*H_ + lane*2);
    r0 += blo(hv);
    r1 += bhi(hv);
    seg++;
  }
  atomAddF(&pooled[cur*H_ + f0], r0);
  atomAddF(&pooled[cur*H_ + f1], r1);
  if(lane==0) atomAddF(&gcnt[cur], (float)seg);
}

// per-graph head — fp32 output
__global__ __launch_bounds__(128) void k_head(const float* __restrict__ pooledacc, const float* __restrict__ gcnt,
    const float* __restrict__ protos, const float* __restrict__ Wc, const float* __restrict__ bc,
    const float* __restrict__ Wd1, const float* __restrict__ bd1, const float* __restrict__ Wd2, const float* __restrict__ bd2,
    float* __restrict__ out){
  const int g = blockIdx.x, t = threadIdx.x;
  __shared__ float p[128], xn[128], red[128], sims[32], es[32], asg[32], pe[128], t1[256];
  __shared__ float nrm;
  float cg_ = fmaxf(gcnt[g], 1.f);
  p[t] = pooledacc[g*128 + t] / cg_;
  __syncthreads();
  red[t] = p[t]*p[t];
  __syncthreads();
  for(int s=64;s>0;s>>=1){ if(t<s) red[t]+=red[t+s]; __syncthreads(); }
  if(t==0) nrm = fmaxf(sqrtf(red[0]), 1e-8f);
  __syncthreads();
  xn[t] = p[t]/nrm;
  __syncthreads();
  if(t<32){
    float s=0.f, pn=0.f;
    for(int f=0;f<128;f++){ float pv=protos[t*128+f]; s += xn[f]*pv; pn += pv*pv; }
    sims[t] = s / fmaxf(sqrtf(pn), 1e-8f);
  }
  __syncthreads();
  if(t<32){
    float mx=-1e30f;
    for(int j=0;j<32;j++) mx = fmaxf(mx, sims[j]);
    es[t] = __expf(sims[t]-mx);
  }
  __syncthreads();
  if(t<32){
    float sm=0.f;
    for(int j=0;j<32;j++) sm += es[j];
    float a = es[t]/fmaxf(sm,1e-20f);
    asg[t] = a;
    out[8832 + g*32 + t] = a;
  }
  __syncthreads();
  {
    float s=0.f;
    for(int pp=0;pp<32;pp++) s += asg[pp]*protos[pp*128+t];
    pe[t] = s;
    out[640 + g*128 + t] = s;
  }
  __syncthreads();
  if(t<10){
    float s = bc[t];
    for(int f=0;f<128;f++) s += pe[f]*Wc[f*10+t];
    out[g*10 + t] = s;
  }
  for(int j=t;j<256;j+=128){
    float s = bd1[j];
    for(int f=0;f<128;f++) s += p[f]*Wd1[f*256+j];
    t1[j] = fmaxf(s, 0.f);
  }
  __syncthreads();
  {
    float s = bd2[t];
    for(int j=0;j<256;j++) s += t1[j]*Wd2[j*128+t];
    out[10880 + g*128 + t] = s;
  }
}

__global__ void k_sentinel(float* out, float code){
  out[0] = code;
}

extern "C" void kernel_launch(void* const* d_in, const int* in_sizes, int n_in,
                              void* d_out, int out_size, void* d_ws, size_t ws_size,
                              hipStream_t stream){
  const float* X    = (const float*)d_in[0];
  const int*  EI    = (const int*)d_in[1];
  const int*  batch = (const int*)d_in[2];
  const int* src = EI;
  const int* dst = EI + E_;

  int iW1,ib1,iWl,iWr,ibs,iWg,ias,iad,ibg,ipr,iWc,ibc,iWd1,ibd1,iWd2,ibd2;
  int ig1,ibe1,im1,iv1,ig2,ibe2,im2,iv2,ig3,ibe3,im3,iv3;
  if(n_in >= 31 && in_sizes[5] == 128){
    iW1=3; ib1=4; ig1=5; ibe1=6; im1=7; iv1=8;
    iWl=9; iWr=10; ibs=11; ig2=12; ibe2=13; im2=14; iv2=15;
    iWg=16; ias=17; iad=18; ibg=19; ig3=20; ibe3=21; im3=22; iv3=23;
    ipr=24; iWc=25; ibc=26; iWd1=27; ibd1=28; iWd2=29; ibd2=30;
  }else{
    iW1=3; ib1=4; iWl=5; iWr=6; ibs=7; iWg=8; ias=9; iad=10; ibg=11;
    ipr=12; iWc=13; ibc=14; iWd1=15; ibd1=16; iWd2=17; ibd2=18;
    ig1=19; ibe1=20; im1=21; iv1=22; ig2=23; ibe2=24; im2=25; iv2=26;
    ig3=27; ibe3=28; im3=29; iv3=30;
  }
  const float* W1 = (const float*)d_in[iW1];   const float* b1 = (const float*)d_in[ib1];
  const float* Wl = (const float*)d_in[iWl];   const float* Wr = (const float*)d_in[iWr];
  const float* bs = (const float*)d_in[ibs];   const float* Wg = (const float*)d_in[iWg];
  const float* a_src = (const float*)d_in[ias]; const float* a_dst = (const float*)d_in[iad];
  const float* bg = (const float*)d_in[ibg];   const float* protos = (const float*)d_in[ipr];
  const float* Wc = (const float*)d_in[iWc];   const float* bc = (const float*)d_in[ibc];
  const float* Wd1 = (const float*)d_in[iWd1]; const float* bd1 = (const float*)d_in[ibd1];
  const float* Wd2 = (const float*)d_in[iWd2]; const float* bd2 = (const float*)d_in[ibd2];
  const float* g1 = (const float*)d_in[ig1];   const float* be1 = (const float*)d_in[ibe1];
  const float* m1 = (const float*)d_in[im1];   const float* v1 = (const float*)d_in[iv1];
  const float* g2 = (const float*)d_in[ig2];   const float* be2 = (const float*)d_in[ibe2];
  const float* m2 = (const float*)d_in[im2];   const float* v2 = (const float*)d_in[iv2];
  const float* g3 = (const float*)d_in[ig3];   const float* be3 = (const float*)d_in[ibe3];
  const float* m3 = (const float*)d_in[im3];   const float* v3 = (const float*)d_in[iv3];

  const size_t NF = (size_t)N_*H_;
  // ints: cnt(N) + row_ptr(N+4) + tmp(N) + esrc(E) + bsum(64) + boff(64)
  const size_t intN = (size_t)3*N_ + 4 + (size_t)E_ + 128;
  // floats: dinv(N) + als4(4N) + ald4(4N) + pooled(G*H) + gcnt(G) + vs3(384) + vd3(384) + sc1(128) + sh1(128)
  const size_t fltN = (size_t)9*N_ + G_*H_ + G_ + 1024;
  const size_t NEED = NF*2*3 + (size_t)N_*384*2 + intN*4 + fltN*4 + (size_t)6*16384*2;
  if(ws_size < NEED){
    k_sentinel<<<1,1,0,stream>>>((float*)d_out, 1000.f + (float)(ws_size>>20));
    return;
  }
  bf16* RA = (bf16*)d_ws;            // h -> h2
  bf16* RB = RA + NF;                // h1
  bf16* RC = RB + NF;                // mean_nb -> h3
  bf16* U  = RC + NF;                // N x 384 aggregated h2-space (3 heads)
  int*  cnt     = (int*)(U + (size_t)N_*384);
  int*  row_ptr = cnt + N_;
  int*  tmp     = row_ptr + (N_+4);
  int*  esrc    = tmp + N_;
  int*  bsum    = esrc + E_;
  int*  boff    = bsum + 64;
  float* dinv   = (float*)(boff + 64);
  float* als4   = dinv + N_;         // N*4 (16B-aligned)
  float* ald4   = als4 + (size_t)N_*4;
  float* pooled = ald4 + (size_t)N_*4;
  float* gcnt   = pooled + (size_t)G_*H_;
  float* vs3    = gcnt + G_;
  float* vd3    = vs3 + 384;
  float* sc1    = vd3 + 384;
  float* sh1    = sc1 + 128;
  unsigned short* WTg = (unsigned short*)(sh1 + 128);

  // ---- weight prep + CSR build ----
  k_wprep<<<(6*16384+255)/256, 256, 0, stream>>>(W1, Wl, Wr, Wg, WTg);
  k_vprep<<<1, 384, 0, stream>>>(Wg, a_src, a_dst, b1, g1, be1, m1, v1, vs3, vd3, sc1, sh1);
  hipMemsetAsync(cnt, 0, N_*sizeof(int), stream);
  hipMemsetAsync(pooled, 0, (size_t)(G_*H_+G_)*sizeof(float), stream);
  k_count<<<(E_+255)/256, 256, 0, stream>>>(dst, cnt);
  k_scan1<<<NB_, 1024, 0, stream>>>(cnt, row_ptr, dinv, bsum);
  k_scan2<<<1, 64, 0, stream>>>(bsum, boff, row_ptr);
  k_scan3<<<(N_+255)/256, 256, 0, stream>>>(row_ptr, boff, tmp);
  k_scatter<<<(E_+255)/256, 256, 0, stream>>>(src, dst, tmp, esrc);

  const int GB = (N_+3)/4;
  const int MB = (N_+63)/64;
  // ---- GCN ----
  k_mm_x<<<MB, 256, 0, stream>>>(X, WTg, RA);
  k_gcn_gather<<<GB, 256, 0, stream>>>(row_ptr, esrc, dinv, RA, sc1, sh1, RB);
  // ---- SAGE (+ fused GAT logits) ----
  k_sage_gather<<<GB, 256, 0, stream>>>(row_ptr, esrc, RB, RC);
  k_sage_mm_att<<<MB, 256, 0, stream>>>(RC, RB, WTg + 16384, WTg + 2*16384, bs, g2, be2, m2, v2,
                                        vs3, vd3, RA, als4, ald4);
  // ---- GAT: h2-space aggregation (edge weights fused), then one K=384 GEMM ----
  k_gat_agg<<<GB, 256, 0, stream>>>(row_ptr, esrc, als4, ald4, RA, U);
  k_gat_mm3<<<MB, 256, 0, stream>>>(U, WTg + 3*16384, bg, g3, be3, m3, v3, RC);
  // ---- pool + head ----
  {
    int waves = (N_ + NPW_ - 1)/NPW_;
    int blocks = (waves + 3)/4;
    k_h3pool<<<blocks, 256, 0, stream>>>(RC, batch, pooled, gcnt);
  }
  k_head<<<G_, 128, 0, stream>>>(pooled, gcnt, protos, Wc, bc, Wd1, bd1, Wd2, bd2, (float*)d_out);
}